// Round 8
// baseline (88.546 us; speedup 1.0000x reference)
//
#include <hip/hip_runtime.h>

// NT-Xent (SimCLR) loss, B=2048, D=256, N=4096, T=0.5, eps=1e-8.
// R8: R7's cooperative launch failed (no output — launch rejected). Same
// fusion via sanctioned device-scope atomics instead: ticket counter after
// partial-writes; the last 16 finisher blocks spin till all 528 done, then
// do the rowlse slices + atomicAdd(out). 2 launches.
// (Deadlock-free without co-residency assumptions: spinners are already
// resident, counter completion needs no future dispatch, and 16 parked
// blocks cannot starve the remaining dispatches on 256 CUs.)
// Fixed harness floor: ~41.5us d_ws poison fill + d_in restore per iter.

#define NROWS 4096
#define DDIM 256
#define BHALF 2048
#define TILE 128
#define BK 64
#define LDP 72      // padded LDS row stride (shorts): 144B = 9*16B, 2-way banks (free)
#define NCB 32      // 4096/128 tile indices
#define NBLK (NCB * (NCB + 1) / 2)   // 528
#define INV_T 2.0f

typedef short bf16x8 __attribute__((ext_vector_type(8)));
typedef float f32x4 __attribute__((ext_vector_type(4)));

__device__ inline unsigned short f2bf(float f) {
    union { float f; unsigned u; } c; c.f = f;
    unsigned u = c.u + 0x7fffu + ((c.u >> 16) & 1u);  // RNE
    return (unsigned short)(u >> 16);
}

// ---- Kernel 1: row-normalize z=[z_i;z_j] into bf16 zn[4096][256] ----------
__global__ __launch_bounds__(256) void k_normalize(
    const float* __restrict__ zi, const float* __restrict__ zj,
    unsigned short* __restrict__ zn, float* __restrict__ out,
    unsigned* __restrict__ done) {
    if (blockIdx.x == 0 && threadIdx.x == 0) { out[0] = 0.f; *done = 0u; }
    const int wave = threadIdx.x >> 6, lane = threadIdx.x & 63;
    const int row = blockIdx.x * 4 + wave;
    const float* src = (row < BHALF) ? (zi + row * DDIM)
                                     : (zj + (row - BHALF) * DDIM);
    const float4 v = ((const float4*)src)[lane];
    float ss = v.x * v.x + v.y * v.y + v.z * v.z + v.w * v.w;
    #pragma unroll
    for (int m = 1; m < 64; m <<= 1) ss += __shfl_xor(ss, m);
    const float scale = 1.0f / fmaxf(sqrtf(ss), 1e-8f);
    ushort4 o;
    o.x = f2bf(v.x * scale); o.y = f2bf(v.y * scale);
    o.z = f2bf(v.z * scale); o.w = f2bf(v.w * scale);
    ((ushort4*)(zn + row * DDIM))[lane] = o;
}

// ---- Kernel 2: upper-triangle sim GEMM + exp-sums + ticketed rowlse tail --
__global__ __launch_bounds__(256) void k_simlse(
    const unsigned short* __restrict__ zn,
    float* __restrict__ partial,     // [NCB][4096], each slot 1 writer
    float* __restrict__ posv,        // [4096]
    unsigned* __restrict__ done,
    float* __restrict__ out) {
    __shared__ unsigned short As[TILE * LDP];
    __shared__ unsigned short Bs[TILE * LDP];
    __shared__ float pscratch[TILE];   // row sums cross-wc (reused in tail)
    __shared__ float cscratch[TILE];   // col sums cross-wr
    __shared__ unsigned sticket;

    // triangle decode: block t -> (bx, by), by >= bx
    int t = blockIdx.x, bx = 0, rem = NCB;
    while (t >= rem) { t -= rem; ++bx; --rem; }
    const int by = bx + t;

    const int tid = threadIdx.x;
    const int wave = tid >> 6, lane = tid & 63;
    const int quad = lane >> 4, l15 = lane & 15;
    const int wr = wave >> 1, wc = wave & 1;
    const int rowBase = bx * TILE;
    const int colBase = by * TILE;

    f32x4 acc[4][4] = {};

    #pragma unroll
    for (int kb = 0; kb < DDIM / BK; ++kb) {
        __syncthreads();
        #pragma unroll
        for (int i = 0; i < 4; ++i) {
            const int flat = tid + i * 256;
            const int r = flat >> 3, c = flat & 7;
            *(bf16x8*)&As[r * LDP + c * 8] =
                *(const bf16x8*)&zn[(rowBase + r) * DDIM + kb * BK + c * 8];
            *(bf16x8*)&Bs[r * LDP + c * 8] =
                *(const bf16x8*)&zn[(colBase + r) * DDIM + kb * BK + c * 8];
        }
        __syncthreads();
        #pragma unroll
        for (int s = 0; s < 2; ++s) {
            bf16x8 af[4], bf[4];
            #pragma unroll
            for (int mt = 0; mt < 4; ++mt)
                af[mt] = *(const bf16x8*)&As[(wr * 64 + mt * 16 + l15) * LDP + s * 32 + quad * 8];
            #pragma unroll
            for (int nt = 0; nt < 4; ++nt)
                bf[nt] = *(const bf16x8*)&Bs[(wc * 64 + nt * 16 + l15) * LDP + s * 32 + quad * 8];
            #pragma unroll
            for (int mt = 0; mt < 4; ++mt)
                #pragma unroll
                for (int nt = 0; nt < 4; ++nt)
                    acc[mt][nt] = __builtin_amdgcn_mfma_f32_16x16x32_bf16(
                        af[mt], bf[nt], acc[mt][nt], 0, 0, 0);
        }
    }

    // Epilogue. C/D layout: col = lane&15, row = quad*4 + r.
    float rsum[4][4];          // [mt][r] row-sums (post-butterfly: all lanes)
    float csum[4] = {};        // [nt] per-lane col partial over 16 rows
    #pragma unroll
    for (int mt = 0; mt < 4; ++mt) {
        #pragma unroll
        for (int r = 0; r < 4; ++r) {
            const int grow = rowBase + wr * 64 + mt * 16 + quad * 4 + r;
            float s = 0.f;
            #pragma unroll
            for (int nt = 0; nt < 4; ++nt) {
                const int gcol = colBase + wc * 64 + nt * 16 + l15;
                const float simv = acc[mt][nt][r] * INV_T;
                const float e = (gcol != grow) ? __expf(simv) : 0.f;
                s += e;
                csum[nt] += e;
                if (gcol == grow + BHALF) {       // only in by==bx+16 blocks
                    posv[grow] = simv;            // sim symmetric -> both rows
                    posv[gcol] = simv;
                }
            }
            s += __shfl_xor(s, 1); s += __shfl_xor(s, 2);
            s += __shfl_xor(s, 4); s += __shfl_xor(s, 8);
            rsum[mt][r] = s;
        }
    }
    // col reduce across quads (row-index bits 4,5 of lane)
    #pragma unroll
    for (int nt = 0; nt < 4; ++nt) {
        csum[nt] += __shfl_xor(csum[nt], 16);
        csum[nt] += __shfl_xor(csum[nt], 32);
    }

    __syncthreads();
    if (wc == 0 && l15 == 0) {
        #pragma unroll
        for (int mt = 0; mt < 4; ++mt)
            #pragma unroll
            for (int r = 0; r < 4; ++r)
                pscratch[wr * 64 + mt * 16 + quad * 4 + r] = rsum[mt][r];
    }
    if (wr == 0 && quad == 0) {
        #pragma unroll
        for (int nt = 0; nt < 4; ++nt)
            cscratch[wc * 64 + nt * 16 + l15] = csum[nt];
    }
    __syncthreads();
    if (wc == 1 && l15 == 0) {    // row-sums -> partial[by][rowBase..]
        #pragma unroll
        for (int mt = 0; mt < 4; ++mt)
            #pragma unroll
            for (int r = 0; r < 4; ++r) {
                const int lr = wr * 64 + mt * 16 + quad * 4 + r;
                partial[by * NROWS + rowBase + lr] = rsum[mt][r] + pscratch[lr];
            }
    }
    if (bx != by && wr == 1 && quad == 0) {  // col-sums -> partial[bx][colBase..]
        #pragma unroll
        for (int nt = 0; nt < 4; ++nt) {
            const int lc = wc * 64 + nt * 16 + l15;
            partial[bx * NROWS + colBase + lc] = csum[nt] + cscratch[lc];
        }
    }

    // ---- Ticketed tail: last 16 finishers do the rowlse slices ----
    __syncthreads();                       // all partial/posv stores issued
    if (tid == 0) {
        __threadfence();                   // device-scope release
        sticket = atomicAdd(done, 1u);
    }
    __syncthreads();
    if (sticket >= NBLK - 16) {
        if (tid == 0) {
            while (__hip_atomic_load(done, __ATOMIC_ACQUIRE,
                                     __HIP_MEMORY_SCOPE_AGENT) < NBLK)
                __builtin_amdgcn_s_sleep(8);
            __threadfence();               // device-scope acquire
        }
        __syncthreads();
        const int slice = (int)sticket - (NBLK - 16);   // 0..15
        const int row = slice * 256 + tid;
        float s = 0.f;
        #pragma unroll
        for (int p = 0; p < NCB; ++p) s += partial[p * NROWS + row];
        float v = __logf(s) - posv[row];
        #pragma unroll
        for (int m = 1; m < 64; m <<= 1) v += __shfl_xor(v, m);
        if ((tid & 63) == 0) pscratch[tid >> 6] = v;
        __syncthreads();
        if (tid == 0)
            atomicAdd(out, (pscratch[0] + pscratch[1] + pscratch[2] + pscratch[3])
                            * (1.0f / (float)NROWS));
    }
}

extern "C" void kernel_launch(void* const* d_in, const int* in_sizes, int n_in,
                              void* d_out, int out_size, void* d_ws, size_t ws_size,
                              hipStream_t stream) {
    const float* zi = (const float*)d_in[0];
    const float* zj = (const float*)d_in[1];
    float* out = (float*)d_out;

    unsigned short* zn = (unsigned short*)d_ws;                    // 2 MB
    float* partial = (float*)((char*)d_ws + NROWS * DDIM * 2);     // 512 KB
    float* posv = partial + NCB * NROWS;                           // 16 KB
    unsigned* done = (unsigned*)(posv + NROWS);                    // 4 B

    k_normalize<<<NROWS / 4, 256, 0, stream>>>(zi, zj, zn, out, done);
    k_simlse<<<NBLK, 256, 0, stream>>>(zn, partial, posv, done, out);
}